// Round 17
// baseline (391.324 us; speedup 1.0000x reference)
//
#include <hip/hip_runtime.h>
#include <hip/hip_bf16.h>

#define TT 512
#define BPW 2                 // batches per wave (8x column replication)
#define NBLK (2048 / BPW)     // 1024 single-wave blocks = 4 per CU
#define OUTD 64

typedef __attribute__((ext_vector_type(8))) short short8;
typedef __attribute__((ext_vector_type(4))) float f32x4;

__device__ __forceinline__ short f2bf(float x) {  // RNE float->bf16 (staging)
    union { float f; unsigned u; } v; v.f = x;
    unsigned r = (v.u + 0x7FFFu + ((v.u >> 16) & 1u)) >> 16;
    return (short)r;
}
__device__ __forceinline__ unsigned cvtpk2(float lo, float hi) {  // pack 2 bf16
    unsigned r;
    asm("v_cvt_pk_bf16_f32 %0, %1, %2" : "=v"(r) : "v"(lo), "v"(hi));
    return r;
}
__device__ __forceinline__ float sigm(float x) {
    return __builtin_amdgcn_rcpf(1.f + __expf(-x));
}
__device__ __forceinline__ float tanh_fast(float x) {
    return 2.f * sigm(2.f * x) - 1.f;
}

#define ACT_UPDATE(acc, c, hval)                                   \
    {                                                              \
        float gi = sigm((acc)[0]);                                 \
        float gf = sigm((acc)[1]);                                 \
        float gg = tanh_fast((acc)[2]);                            \
        float go = sigm((acc)[3]);                                 \
        (c) = gf * (c) + gi * gg;                                  \
        (hval) = go * tanh_fast((c));                              \
    }

#define MFMA __builtin_amdgcn_mfma_f32_16x16x32_bf16

// select acc[tsel] without dynamic indexing (R14-proven mux tree)
#define SELECT(mine, acc)                                          \
    f32x4 mine;                                                    \
    {                                                              \
        f32x4 m01 = (tsel & 1) ? (acc)[1] : (acc)[0];              \
        f32x4 m23 = (tsel & 1) ? (acc)[3] : (acc)[2];              \
        f32x4 m45 = (tsel & 1) ? (acc)[5] : (acc)[4];              \
        f32x4 m67 = (tsel & 1) ? (acc)[7] : (acc)[6];              \
        f32x4 mA  = (tsel & 2) ? m23 : m01;                        \
        f32x4 mB  = (tsel & 2) ? m67 : m45;                        \
        mine = (tsel & 4) ? mB : mA;                               \
    }

// R14-proven repack: lane owns h of (u=4*tsel+kg, b=col&1); B-frag slot j
// needs h[k=kg*8+j][b]; src lane = 16*(j&3)+4*kg+2*(j>>2)+b.
#define REPACK(h, frag)                                            \
    {                                                              \
        const int base = 4 * kg + b;                               \
        float s0 = __shfl((h), base);                              \
        float s1 = __shfl((h), base + 16);                         \
        float s2 = __shfl((h), base + 32);                         \
        float s3 = __shfl((h), base + 48);                         \
        float s4 = __shfl((h), base + 2);                          \
        float s5 = __shfl((h), base + 18);                         \
        float s6 = __shfl((h), base + 34);                         \
        float s7 = __shfl((h), base + 50);                         \
        union { unsigned u[4]; short8 s; } hu;                     \
        hu.u[0] = cvtpk2(s0, s1); hu.u[1] = cvtpk2(s2, s3);        \
        hu.u[2] = cvtpk2(s4, s5); hu.u[3] = cvtpk2(s6, s7);        \
        (frag) = hu.s;                                             \
    }

__global__ __launch_bounds__(64, 1) void lstm2_nobarrier_kernel(
    const float* __restrict__ imu,
    const float* __restrict__ w_ih0, const float* __restrict__ w_hh0,
    const float* __restrict__ b_ih0, const float* __restrict__ b_hh0,
    const float* __restrict__ w_ih1, const float* __restrict__ w_hh1,
    const float* __restrict__ b_ih1, const float* __restrict__ b_hh1,
    const float* __restrict__ wf, const float* __restrict__ bf,
    const float* __restrict__ wn, const float* __restrict__ bn,
    float* __restrict__ out)
{
    const int l    = threadIdx.x;     // single wave
    const int col  = l & 15;
    const int kg   = l >> 4;
    const int b    = col & 1;         // batch
    const int tsel = col >> 1;        // owned tile after select
    const int unit = 4 * tsel + kg;   // owned hidden unit (per layer)

    __shared__ __align__(16) short xfrag[TT + 1][BPW][8];  // [t][b][k] bf16; +1 pad
    __shared__ __align__(16) float lasth[BPW][36];

    // ---- stage x (2 batches) + zero pad row
    {
        const int bg0 = blockIdx.x * BPW;
        for (int p = l; p < BPW * TT; p += 64) {
            const int bb = p >> 9;           // 0..1
            const int t  = p & (TT - 1);
            const float* src = imu + ((size_t)(bg0 + bb) * TT + t) * 6;
            float2 a0 = *(const float2*)(src);
            float2 a1 = *(const float2*)(src + 2);
            float2 a2 = *(const float2*)(src + 4);
            unsigned* dst = (unsigned*)&xfrag[t][bb][0];
            dst[0] = (unsigned short)f2bf(a0.x) | ((unsigned)(unsigned short)f2bf(a0.y) << 16);
            dst[1] = (unsigned short)f2bf(a1.x) | ((unsigned)(unsigned short)f2bf(a1.y) << 16);
            dst[2] = (unsigned short)f2bf(a2.x) | ((unsigned)(unsigned short)f2bf(a2.y) << 16);
            dst[3] = 0u;
        }
        short* px = &xfrag[TT][0][0];
        if (l < BPW * 8) px[l] = 0;
    }

    // ---- A-fragments for BOTH layers (R14-proven mapping:
    // row m=col -> gate G=(m&3)*32+4*tp+(m>>2); acc[tp] reg r = gate-type r)
    short8 AX1[8], AS1[8], AX2[8], AS2[8];
    f32x4 bias1, bias2;
    #pragma unroll
    for (int tp = 0; tp < 8; ++tp) {
        const int G = (col & 3) * 32 + 4 * tp + (col >> 2);
        #pragma unroll
        for (int j = 0; j < 8; ++j) {
            AX1[tp][j] = (kg == 0 && j < 6) ? f2bf(w_ih0[G * 6 + j]) : (short)0;
            AS1[tp][j] = f2bf(w_hh0[G * 32 + kg * 8 + j]);
            AX2[tp][j] = f2bf(w_ih1[G * 32 + kg * 8 + j]);
            AS2[tp][j] = f2bf(w_hh1[G * 32 + kg * 8 + j]);
        }
    }
    #pragma unroll
    for (int r = 0; r < 4; ++r) {
        bias1[r] = b_ih0[r * 32 + unit] + b_hh0[r * 32 + unit];
        bias2[r] = b_ih1[r * 32 + unit] + b_hh1[r * 32 + unit];
    }

    float c1 = 0.f, c2 = 0.f;
    short8 h1frag = (short8)0, h2frag = (short8)0;
    float h2last = 0.f;
    const f32x4 zf = {0.f, 0.f, 0.f, 0.f};

    __syncthreads();   // x staged (cheap: single wave)

    short8 xv = *(const short8*)&xfrag[0][b][0];

    // ======== main loop: BOTH layers per iteration, ZERO barriers ========
    #pragma unroll 1
    for (int t = 0; t < TT; ++t) {
        // L1 gates: Wih0*x + Whh0*h1
        f32x4 a1[8];
        #pragma unroll
        for (int tp = 0; tp < 8; ++tp) a1[tp] = MFMA(AX1[tp], xv, zf, 0, 0, 0);
        // L2 recurrent half EARLY (independent of h1frag -> hides L1 ACT chain)
        f32x4 a2[8];
        #pragma unroll
        for (int tp = 0; tp < 8; ++tp) a2[tp] = MFMA(AS2[tp], h2frag, zf, 0, 0, 0);
        #pragma unroll
        for (int tp = 0; tp < 8; ++tp) a1[tp] = MFMA(AS1[tp], h1frag, a1[tp], 0, 0, 0);
        // prefetch next x (no user until next iteration)
        xv = *(const short8*)&xfrag[t + 1][b][0];

        // L1 cell update (in-lane; 1 valid (unit,batch) per lane)
        {
            SELECT(m1, a1);
            m1 += bias1;
            float h1v;
            ACT_UPDATE(m1, c1, h1v);
            REPACK(h1v, h1frag);
        }

        // L2 input half + cell update
        #pragma unroll
        for (int tp = 0; tp < 8; ++tp) a2[tp] = MFMA(AX2[tp], h1frag, a2[tp], 0, 0, 0);
        {
            SELECT(m2, a2);
            m2 += bias2;
            float h2v;
            ACT_UPDATE(m2, c2, h2v);
            REPACK(h2v, h2frag);
            h2last = h2v;
        }
    }

    lasth[b][unit] = h2last;   // all 64 lanes valid: 32 units x 2 batches
    __syncthreads();

    // ======== heads: 2 reps x 64 threads = 2 batches x 64 outputs ========
    #pragma unroll
    for (int rep = 0; rep < 2; ++rep) {
        const int idx = l + rep * 64;      // 0..127
        const int bb  = idx >> 6;          // 0..1 (wave-uniform)
        const int o   = idx & 63;
        float accF = bf[o], accN = bn[o];
        const float4* wf4 = (const float4*)(wf + o * 32);
        const float4* wn4 = (const float4*)(wn + o * 32);
        const float4* hv4 = (const float4*)&lasth[bb][0];
        #pragma unroll
        for (int k = 0; k < 8; ++k) {
            float4 h4 = hv4[k];
            float4 f4 = wf4[k];
            float4 n4 = wn4[k];
            accF += f4.x * h4.x + f4.y * h4.y + f4.z * h4.z + f4.w * h4.w;
            accN += n4.x * h4.x + n4.y * h4.y + n4.z * h4.z + n4.w * h4.w;
        }
        const size_t bg = (size_t)blockIdx.x * BPW + bb;
        out[bg * OUTD + o] = accF;
        out[(size_t)2048 * OUTD + bg * OUTD + o] = __expf(accN);
    }
}

extern "C" void kernel_launch(void* const* d_in, const int* in_sizes, int n_in,
                              void* d_out, int out_size, void* d_ws, size_t ws_size,
                              hipStream_t stream) {
    const float* imu   = (const float*)d_in[0];
    const float* w_ih0 = (const float*)d_in[1];
    const float* w_hh0 = (const float*)d_in[2];
    const float* b_ih0 = (const float*)d_in[3];
    const float* b_hh0 = (const float*)d_in[4];
    const float* w_ih1 = (const float*)d_in[5];
    const float* w_hh1 = (const float*)d_in[6];
    const float* b_ih1 = (const float*)d_in[7];
    const float* b_hh1 = (const float*)d_in[8];
    const float* wf    = (const float*)d_in[9];
    const float* bf    = (const float*)d_in[10];
    const float* wn    = (const float*)d_in[11];
    const float* bn    = (const float*)d_in[12];
    float* out = (float*)d_out;

    lstm2_nobarrier_kernel<<<dim3(NBLK), dim3(64), 0, stream>>>(
        imu, w_ih0, w_hh0, b_ih0, b_hh0,
        w_ih1, w_hh1, b_ih1, b_hh1,
        wf, bf, wn, bn, out);
}